// Round 8
// baseline (413.258 us; speedup 1.0000x reference)
//
#include <hip/hip_runtime.h>
#include <stdint.h>

#define IN_F 256
#define OUT_F 128
#define NCOLS 1024   // 768 slices + 128 sum-slice + 128 self (all bf16)
#define BM 64
#define BN 128
#define BK 32

using bf16x8 = __attribute__((ext_vector_type(8))) __bf16;
using f32x4  = __attribute__((ext_vector_type(4))) float;

static __device__ __forceinline__ unsigned short f2bf(float f) {
    unsigned u = __float_as_uint(f);
    u = u + 0x7fffu + ((u >> 16) & 1u);   // RNE
    return (unsigned short)(u >> 16);
}
static __device__ __forceinline__ float bf_lo(unsigned u) { return __uint_as_float(u << 16); }
static __device__ __forceinline__ float bf_hi(unsigned u) { return __uint_as_float(u & 0xffff0000u); }

static __device__ __forceinline__ void async_load16(const void* g, void* l) {
    __builtin_amdgcn_global_load_lds(
        (__attribute__((address_space(1))) void*)g,
        (__attribute__((address_space(3))) void*)l,
        16, 0, 0);
}

// ne (worklist entries) for an edge given its 6 degrees
static __device__ __forceinline__ int edge_ne(const float* dg, unsigned& zm) {
    zm = 0;
#pragma unroll
    for (int i = 0; i < 6; ++i) if (!(dg[i] > 0.f)) zm |= (1u << i);
    int z = __popc(zm);
    return (z == 6) ? 0 : ((z <= 2) ? (1 + z) : (6 - z));
}

// ---- h (f32) -> bf16 ----
__global__ void k_conv_h(const float* __restrict__ h, unsigned short* __restrict__ hb, int total8) {
    int i = blockIdx.x * blockDim.x + threadIdx.x;
    if (i >= total8) return;
    const float4* src = ((const float4*)h) + (size_t)i * 2;
    float4 a = src[0], b = src[1];
    union { unsigned short us[8]; uint4 v; } u;
    u.us[0] = f2bf(a.x); u.us[1] = f2bf(a.y); u.us[2] = f2bf(a.z); u.us[3] = f2bf(a.w);
    u.us[4] = f2bf(b.x); u.us[5] = f2bf(b.y); u.us[6] = f2bf(b.z); u.us[7] = f2bf(b.w);
    ((uint4*)hb)[i] = u.v;
}

// ---- Wt[1024][256] = [W_node | sum(slices) | W_self]^T bf16; bvec[1024] ----
__global__ void k_conv_w(const float* __restrict__ Wn, const float* __restrict__ Ws,
                         const float* __restrict__ bn, const float* __restrict__ bs,
                         unsigned short* __restrict__ Wt, float* __restrict__ bvec, int total) {
    int i = blockIdx.x * blockDim.x + threadIdx.x;   // i = k*1024 + c
    if (i >= total) return;
    int k = i >> 10, c = i & 1023;
    float v;
    if (c < 768) {
        v = Wn[(size_t)k * 768 + c];
    } else if (c < 896) {
        int j = c - 768; v = 0.f;
#pragma unroll
        for (int s = 0; s < 6; ++s) v += Wn[(size_t)k * 768 + s * 128 + j];
    } else {
        v = Ws[(size_t)k * 128 + (c - 896)];
    }
    Wt[(size_t)c * IN_F + k] = f2bf(v);

    if (i < NCOLS) {
        float b;
        if (i < 768) b = bn[i];
        else if (i < 896) {
            int j = i - 768; b = 0.f;
#pragma unroll
            for (int s = 0; s < 6; ++s) b += bn[s * 128 + j];
        } else b = bs[i - 896];
        bvec[i] = b;
    }
}

// ---- GEMM (R5-proven): XCD-chunked swizzle + LDS-staged coalesced C-store ----
__global__ void __launch_bounds__(256) k_gemm(
    const unsigned short* __restrict__ hb,
    const unsigned short* __restrict__ Wt,
    const float* __restrict__ bvec,
    const float* __restrict__ norm,
    unsigned short* __restrict__ P, int N, int rowsPerXcd)
{
    __shared__ char lds[(BM + BN) * BK * 2];       // 12 KB (A 4 KB, B 8 KB)
    __shared__ unsigned short Pst[BM * BN];        // 16 KB store staging
    char* Ab = lds;
    char* Bb = lds + BM * BK * 2;

    const int f  = blockIdx.x;
    const int xc = f & 7;
    const int j  = f >> 3;
    const int rs = xc * rowsPerXcd + (j >> 3);
    const int ct = j & 7;
    const int r0 = rs * BM;
    if (r0 >= N) return;
    const int c0 = ct * BN;

    const int tid = threadIdx.x;
    const int wid = tid >> 6, lane = tid & 63;
    const int lrow = lane & 15, s = lane >> 4;
    const int wr = wid >> 1, wc = wid & 1;

    const int arow = tid >> 2;
    const int achunk = (tid & 3) ^ ((arow >> 1) & 3);
    int agrow = r0 + arow; if (agrow >= N) agrow = N - 1;
    const unsigned short* aseg = hb + (size_t)agrow * IN_F + achunk * 8;

    const int bcol0 = tid >> 2;
    const int bchunk0 = (tid & 3) ^ ((bcol0 >> 1) & 3);
    const unsigned short* bseg0 = Wt + (size_t)(c0 + bcol0) * IN_F + bchunk0 * 8;
    const int idx1 = tid + 256;
    const int bcol1 = idx1 >> 2;
    const int bchunk1 = (idx1 & 3) ^ ((bcol1 >> 1) & 3);
    const unsigned short* bseg1 = Wt + (size_t)(c0 + bcol1) * IN_F + bchunk1 * 8;

    int a_off[2], b_off[4];
#pragma unroll
    for (int m = 0; m < 2; ++m) {
        int rl = wr * 32 + m * 16 + lrow;
        a_off[m] = rl * 64 + ((s ^ ((rl >> 1) & 3)) << 4);
    }
#pragma unroll
    for (int n = 0; n < 4; ++n) {
        int cl = wc * 64 + n * 16 + lrow;
        b_off[n] = cl * 64 + ((s ^ ((cl >> 1) & 3)) << 4);
    }

    float nrmv[2][4];
#pragma unroll
    for (int m = 0; m < 2; ++m)
#pragma unroll
        for (int r = 0; r < 4; ++r) {
            int rg = r0 + wr * 32 + m * 16 + s * 4 + r;
            nrmv[m][r] = norm[rg < N ? rg : N - 1];
        }

    f32x4 acc[2][4] = {};

    for (int kk = 0; kk < IN_F / BK; ++kk) {
        async_load16(aseg + kk * BK, Ab + tid * 16);
        async_load16(bseg0 + kk * BK, Bb + tid * 16);
        async_load16(bseg1 + kk * BK, Bb + (tid + 256) * 16);
        __syncthreads();

        bf16x8 af[2], bfv[4];
#pragma unroll
        for (int m = 0; m < 2; ++m) af[m] = *(const bf16x8*)(Ab + a_off[m]);
#pragma unroll
        for (int n = 0; n < 4; ++n) bfv[n] = *(const bf16x8*)(Bb + b_off[n]);
#pragma unroll
        for (int m = 0; m < 2; ++m)
#pragma unroll
            for (int n = 0; n < 4; ++n)
                acc[m][n] = __builtin_amdgcn_mfma_f32_16x16x32_bf16(af[m], bfv[n], acc[m][n], 0, 0, 0);
        __syncthreads();
    }

    const bool doNorm = (c0 < 896);
#pragma unroll
    for (int m = 0; m < 2; ++m) {
        const int rowl = wr * 32 + m * 16 + s * 4;
#pragma unroll
        for (int n = 0; n < 4; ++n) {
            const int col = wc * 64 + n * 16 + lrow;
            const float bv = bvec[c0 + col];
            const int chunk = col >> 3, cb = col & 7;
#pragma unroll
            for (int r = 0; r < 4; ++r) {
                float v = acc[m][n][r] + bv;
                if (doNorm) v *= nrmv[m][r];
                const int row = rowl + r;
                Pst[row * 128 + ((chunk ^ (row & 7)) * 8 + cb)] = f2bf(v);
            }
        }
    }
    __syncthreads();

    const int ch = tid & 15;
#pragma unroll
    for (int rr = 0; rr < 4; ++rr) {
        const int rl = rr * 16 + (tid >> 4);
        const int rg = r0 + rl;
        if (rg < N) {
            uint4 v = *(const uint4*)&Pst[rl * 128 + ((ch ^ (rl & 7)) * 8)];
            *(uint4*)(P + (size_t)rg * NCOLS + c0 + ch * 8) = v;
        }
    }
}

// ---- histogram of ENTRY counts per dst ----
__global__ void k_hist(const int* __restrict__ dst, const float* __restrict__ degrees,
                       int* __restrict__ counts, int E) {
    int e = blockIdx.x * blockDim.x + threadIdx.x;
    if (e >= E) return;
    float dg[6];
#pragma unroll
    for (int i = 0; i < 6; ++i) dg[i] = degrees[(size_t)e * 6 + i];
    unsigned zm;
    int ne = edge_ne(dg, zm);
    if (ne) atomicAdd(&counts[dst[e]], ne);
}

// ---- 3-phase exclusive scan over counts[N] ----
__global__ void __launch_bounds__(256) k_scan_a(const int* __restrict__ counts,
                                                int* __restrict__ offs,
                                                int* __restrict__ bsum, int N) {
    __shared__ int sm[256];
    int tid = threadIdx.x;
    int i = blockIdx.x * 256 + tid;
    int v = (i < N) ? counts[i] : 0;
    sm[tid] = v;
    __syncthreads();
#pragma unroll
    for (int st = 1; st < 256; st <<= 1) {
        int t = (tid >= st) ? sm[tid - st] : 0;
        __syncthreads();
        sm[tid] += t;
        __syncthreads();
    }
    if (i < N) offs[i] = sm[tid] - v;
    if (tid == 255) bsum[blockIdx.x] = sm[255];
}

__global__ void __launch_bounds__(256) k_scan_b(int* __restrict__ bsum, int NB) {
    __shared__ int sm[256];
    int tid = threadIdx.x;
    int v = (tid < NB) ? bsum[tid] : 0;
    sm[tid] = v;
    __syncthreads();
#pragma unroll
    for (int st = 1; st < 256; st <<= 1) {
        int t = (tid >= st) ? sm[tid - st] : 0;
        __syncthreads();
        sm[tid] += t;
        __syncthreads();
    }
    if (tid < NB) bsum[tid] = sm[tid] - v;
}

__global__ void k_scan_c(int* __restrict__ offs, const int* __restrict__ bsum,
                         int* __restrict__ cursor, int N) {
    int i = blockIdx.x * 256 + threadIdx.x;
    if (i >= N) return;
    int o = offs[i] + bsum[blockIdx.x];
    offs[i] = o;
    cursor[i] = o;
}

// ---- scatter: base-term atomics into D[dst][6] + entry-CSR build ----
__global__ void k_scatter(const int* __restrict__ src, const int* __restrict__ dst,
                          const float* __restrict__ degrees, const float* __restrict__ norm,
                          float* __restrict__ D, int* __restrict__ cursor,
                          unsigned* __restrict__ entries, int E) {
    int e = blockIdx.x * blockDim.x + threadIdx.x;
    if (e >= E) return;
    const int d = dst[e];
    const int s = src[e];
    float dg[6];
#pragma unroll
    for (int i = 0; i < 6; ++i) dg[i] = degrees[(size_t)e * 6 + i];
    unsigned zm;
    const int ne = edge_ne(dg, zm);
    const int z = __popc(zm);
    const float nr = norm[s];

#pragma unroll
    for (int i = 0; i < 6; ++i)
        if (dg[i] > 0.f) atomicAdd(&D[(size_t)d * 6 + i], nr * dg[i]);

    if (ne == 0) return;
    int slot = atomicAdd(&cursor[d], ne);
    const unsigned base = (unsigned)s * 512u;     // dword index of P row
    if (z <= 2) {
        entries[slot++] = base + 384u;            // + sum-slice
#pragma unroll
        for (int i = 0; i < 6; ++i)
            if ((zm >> i) & 1u) entries[slot++] = (base + i * 64u) | 0x80000000u;  // - zero slices
    } else {
#pragma unroll
        for (int i = 0; i < 6; ++i)
            if (!((zm >> i) & 1u)) entries[slot++] = base + i * 64u;               // + nonzero slices
    }
}

// ---- aggregate v5: pure gather loop (all per-edge VALU hoisted to scatter) ----
__global__ void __launch_bounds__(256) k_aggregate(
    const unsigned* __restrict__ Pd,             // P as dwords
    const int* __restrict__ row_start, const int* __restrict__ counts,
    const unsigned* __restrict__ entries,
    const float* __restrict__ D,
    const float* __restrict__ norm, const float* __restrict__ W_edge,
    const float* __restrict__ bias, float* __restrict__ out, int N)
{
    __shared__ unsigned EB[4][64];
    const int wid = threadIdx.x >> 6;
    const int n = blockIdx.x * 4 + wid;
    if (n >= N) return;
    const int lane = threadIdx.x & 63;
    unsigned* eb = EB[wid];

    // base term: b = sum_i D[n][i] * W_edge[i][col]
    float b0 = 0.f, b1 = 0.f;
#pragma unroll
    for (int i = 0; i < 6; ++i) {
        const float dv = D[(size_t)n * 6 + i];
        float2 w = *(const float2*)(W_edge + i * OUT_F + lane * 2);
        b0 = fmaf(dv, w.x, b0);
        b1 = fmaf(dv, w.y, b1);
    }

    const int beg = row_start[n];
    const int end = beg + counts[n];
    float g0 = 0.f, g1 = 0.f;

    for (int p0 = beg; p0 < end; p0 += 64) {
        if (p0 + lane < end) eb[lane] = entries[p0 + lane];
        asm volatile("s_waitcnt lgkmcnt(0)" ::: "memory");
        __builtin_amdgcn_sched_barrier(0);

        const int cnt = min(64, end - p0);
        int j = 0;
        for (; j + 8 <= cnt; j += 8) {
#pragma unroll
            for (int q = 0; q < 8; ++q) {
                unsigned e0 = eb[j + q];
                unsigned u0 = Pd[(e0 & 0x7fffffffu) + lane];
                float s0 = __uint_as_float(0x3f800000u | (e0 & 0x80000000u));
                g0 = fmaf(s0, bf_lo(u0), g0);
                g1 = fmaf(s0, bf_hi(u0), g1);
            }
        }
        for (; j < cnt; ++j) {
            unsigned e0 = eb[j];
            unsigned u0 = Pd[(e0 & 0x7fffffffu) + lane];
            float s0 = __uint_as_float(0x3f800000u | (e0 & 0x80000000u));
            g0 = fmaf(s0, bf_lo(u0), g0);
            g1 = fmaf(s0, bf_hi(u0), g1);
        }
    }

    // fused epilogue: relu(accum*norm + self + bias)
    const unsigned us = Pd[(size_t)n * 512 + 448 + lane];
    const float nd = norm[n];
    const float2 bv = *(const float2*)(bias + lane * 2);
    float2 o;
    o.x = fmaxf((g0 + b0) * nd + bf_lo(us) + bv.x, 0.f);
    o.y = fmaxf((g1 + b1) * nd + bf_hi(us) + bv.y, 0.f);
    *(float2*)(out + (size_t)n * OUT_F + lane * 2) = o;
}

extern "C" void kernel_launch(void* const* d_in, const int* in_sizes, int n_in,
                              void* d_out, int out_size, void* d_ws, size_t ws_size,
                              hipStream_t stream)
{
    const float* h       = (const float*)d_in[0];
    const float* degrees = (const float*)d_in[1];
    const float* norm    = (const float*)d_in[2];
    const int*   src     = (const int*)d_in[3];
    const int*   dst     = (const int*)d_in[4];
    const float* W_self  = (const float*)d_in[5];
    const float* b_self  = (const float*)d_in[6];
    const float* W_node  = (const float*)d_in[7];
    const float* b_node  = (const float*)d_in[8];
    const float* W_edge  = (const float*)d_in[9];
    const float* bias    = (const float*)d_in[10];
    float* out = (float*)d_out;

    const int N = in_sizes[2];   // norm [N,1]
    const int E = in_sizes[3];   // src [E]
    const int NB = (N + 255) / 256;

    char* ws = (char*)d_ws;
    size_t off = 0;
    auto alloc = [&](size_t sz) { size_t o = off; off = (off + sz + 255) & ~(size_t)255; return o; };
    unsigned short* P      = (unsigned short*)(ws + alloc((size_t)N * NCOLS * 2)); // 102.4 MB
    unsigned short* hb     = (unsigned short*)(ws + alloc((size_t)N * IN_F * 2));  // 25.6 MB
    unsigned short* Wt     = (unsigned short*)(ws + alloc((size_t)NCOLS * IN_F * 2));
    float*          bvec   = (float*)(ws + alloc(NCOLS * 4));
    float*          D      = (float*)(ws + alloc((size_t)N * 6 * 4));              // 1.2 MB
    int*            counts = (int*)(ws + alloc((size_t)N * 4));
    int*            offs   = (int*)(ws + alloc((size_t)N * 4));
    int*            cursor = (int*)(ws + alloc((size_t)N * 4));
    int*            bsum   = (int*)(ws + alloc((size_t)NB * 4));
    unsigned*       entries= (unsigned*)(ws + alloc((size_t)E * 3 * 4));           // 9.6 MB cap

    hipMemsetAsync(counts, 0, (size_t)N * 4, stream);
    hipMemsetAsync(D, 0, (size_t)N * 6 * 4, stream);

    int t8 = N * (IN_F / 8);
    k_conv_h<<<(t8 + 255) / 256, 256, 0, stream>>>(h, hb, t8);

    int tw = IN_F * NCOLS;
    k_conv_w<<<(tw + 255) / 256, 256, 0, stream>>>(W_node, W_self, b_node, b_self, Wt, bvec, tw);

    const int R  = (N + BM - 1) / BM;
    const int RP = (R + 7) / 8;
    k_gemm<<<RP * 8 * 8, 256, 0, stream>>>(hb, Wt, bvec, norm, P, N, RP);

    k_hist<<<(E + 255) / 256, 256, 0, stream>>>(dst, degrees, counts, E);
    k_scan_a<<<NB, 256, 0, stream>>>(counts, offs, bsum, N);
    k_scan_b<<<1, 256, 0, stream>>>(bsum, NB);
    k_scan_c<<<NB, 256, 0, stream>>>(offs, bsum, cursor, N);
    k_scatter<<<(E + 255) / 256, 256, 0, stream>>>(src, dst, degrees, norm, D, cursor, entries, E);

    k_aggregate<<<(N + 3) / 4, 256, 0, stream>>>((const unsigned*)P, offs, counts, entries, D,
                                                 norm, W_edge, bias, out, N);
}

// Round 9
// 342.921 us; speedup vs baseline: 1.2051x; 1.2051x over previous
//
#include <hip/hip_runtime.h>
#include <stdint.h>

#define IN_F 256
#define OUT_F 128
#define NCOLS 1024   // 768 slices + 128 sum-slice + 128 self (all bf16)
#define BM 64
#define BN 128
#define BK 32

using bf16x8 = __attribute__((ext_vector_type(8))) __bf16;
using f32x4  = __attribute__((ext_vector_type(4))) float;

static __device__ __forceinline__ unsigned short f2bf(float f) {
    unsigned u = __float_as_uint(f);
    u = u + 0x7fffu + ((u >> 16) & 1u);   // RNE
    return (unsigned short)(u >> 16);
}
static __device__ __forceinline__ float bf_lo(unsigned u) { return __uint_as_float(u << 16); }
static __device__ __forceinline__ float bf_hi(unsigned u) { return __uint_as_float(u & 0xffff0000u); }

static __device__ __forceinline__ void async_load16(const void* g, void* l) {
    __builtin_amdgcn_global_load_lds(
        (__attribute__((address_space(1))) void*)g,
        (__attribute__((address_space(3))) void*)l,
        16, 0, 0);
}

// worklist entry count for an edge given zero-mask
static __device__ __forceinline__ int ne_of(unsigned zm) {
    int z = __popc(zm);
    return (z == 6) ? 0 : ((z <= 2) ? (1 + z) : (6 - z));
}

// ---- h (f32) -> bf16 ----
__global__ void k_conv_h(const float* __restrict__ h, unsigned short* __restrict__ hb, int total8) {
    int i = blockIdx.x * blockDim.x + threadIdx.x;
    if (i >= total8) return;
    const float4* src = ((const float4*)h) + (size_t)i * 2;
    float4 a = src[0], b = src[1];
    union { unsigned short us[8]; uint4 v; } u;
    u.us[0] = f2bf(a.x); u.us[1] = f2bf(a.y); u.us[2] = f2bf(a.z); u.us[3] = f2bf(a.w);
    u.us[4] = f2bf(b.x); u.us[5] = f2bf(b.y); u.us[6] = f2bf(b.z); u.us[7] = f2bf(b.w);
    ((uint4*)hb)[i] = u.v;
}

// ---- Wt[1024][256] = [W_node | sum(slices) | W_self]^T bf16; bvec[1024] ----
__global__ void k_conv_w(const float* __restrict__ Wn, const float* __restrict__ Ws,
                         const float* __restrict__ bn, const float* __restrict__ bs,
                         unsigned short* __restrict__ Wt, float* __restrict__ bvec, int total) {
    int i = blockIdx.x * blockDim.x + threadIdx.x;   // i = k*1024 + c
    if (i >= total) return;
    int k = i >> 10, c = i & 1023;
    float v;
    if (c < 768) {
        v = Wn[(size_t)k * 768 + c];
    } else if (c < 896) {
        int j = c - 768; v = 0.f;
#pragma unroll
        for (int s = 0; s < 6; ++s) v += Wn[(size_t)k * 768 + s * 128 + j];
    } else {
        v = Ws[(size_t)k * 128 + (c - 896)];
    }
    Wt[(size_t)c * IN_F + k] = f2bf(v);

    if (i < NCOLS) {
        float b;
        if (i < 768) b = bn[i];
        else if (i < 896) {
            int j = i - 768; b = 0.f;
#pragma unroll
            for (int s = 0; s < 6; ++s) b += bn[s * 128 + j];
        } else b = bs[i - 896];
        bvec[i] = b;
    }
}

// ---- GEMM (R5-proven): XCD-chunked swizzle + LDS-staged coalesced C-store ----
__global__ void __launch_bounds__(256) k_gemm(
    const unsigned short* __restrict__ hb,
    const unsigned short* __restrict__ Wt,
    const float* __restrict__ bvec,
    const float* __restrict__ norm,
    unsigned short* __restrict__ P, int N, int rowsPerXcd)
{
    __shared__ char lds[(BM + BN) * BK * 2];       // 12 KB (A 4 KB, B 8 KB)
    __shared__ unsigned short Pst[BM * BN];        // 16 KB store staging
    char* Ab = lds;
    char* Bb = lds + BM * BK * 2;

    const int f  = blockIdx.x;
    const int xc = f & 7;
    const int j  = f >> 3;
    const int rs = xc * rowsPerXcd + (j >> 3);
    const int ct = j & 7;
    const int r0 = rs * BM;
    if (r0 >= N) return;
    const int c0 = ct * BN;

    const int tid = threadIdx.x;
    const int wid = tid >> 6, lane = tid & 63;
    const int lrow = lane & 15, s = lane >> 4;
    const int wr = wid >> 1, wc = wid & 1;

    const int arow = tid >> 2;
    const int achunk = (tid & 3) ^ ((arow >> 1) & 3);
    int agrow = r0 + arow; if (agrow >= N) agrow = N - 1;
    const unsigned short* aseg = hb + (size_t)agrow * IN_F + achunk * 8;

    const int bcol0 = tid >> 2;
    const int bchunk0 = (tid & 3) ^ ((bcol0 >> 1) & 3);
    const unsigned short* bseg0 = Wt + (size_t)(c0 + bcol0) * IN_F + bchunk0 * 8;
    const int idx1 = tid + 256;
    const int bcol1 = idx1 >> 2;
    const int bchunk1 = (idx1 & 3) ^ ((bcol1 >> 1) & 3);
    const unsigned short* bseg1 = Wt + (size_t)(c0 + bcol1) * IN_F + bchunk1 * 8;

    int a_off[2], b_off[4];
#pragma unroll
    for (int m = 0; m < 2; ++m) {
        int rl = wr * 32 + m * 16 + lrow;
        a_off[m] = rl * 64 + ((s ^ ((rl >> 1) & 3)) << 4);
    }
#pragma unroll
    for (int n = 0; n < 4; ++n) {
        int cl = wc * 64 + n * 16 + lrow;
        b_off[n] = cl * 64 + ((s ^ ((cl >> 1) & 3)) << 4);
    }

    float nrmv[2][4];
#pragma unroll
    for (int m = 0; m < 2; ++m)
#pragma unroll
        for (int r = 0; r < 4; ++r) {
            int rg = r0 + wr * 32 + m * 16 + s * 4 + r;
            nrmv[m][r] = norm[rg < N ? rg : N - 1];
        }

    f32x4 acc[2][4] = {};

    for (int kk = 0; kk < IN_F / BK; ++kk) {
        async_load16(aseg + kk * BK, Ab + tid * 16);
        async_load16(bseg0 + kk * BK, Bb + tid * 16);
        async_load16(bseg1 + kk * BK, Bb + (tid + 256) * 16);
        __syncthreads();

        bf16x8 af[2], bfv[4];
#pragma unroll
        for (int m = 0; m < 2; ++m) af[m] = *(const bf16x8*)(Ab + a_off[m]);
#pragma unroll
        for (int n = 0; n < 4; ++n) bfv[n] = *(const bf16x8*)(Bb + b_off[n]);
#pragma unroll
        for (int m = 0; m < 2; ++m)
#pragma unroll
            for (int n = 0; n < 4; ++n)
                acc[m][n] = __builtin_amdgcn_mfma_f32_16x16x32_bf16(af[m], bfv[n], acc[m][n], 0, 0, 0);
        __syncthreads();
    }

    const bool doNorm = (c0 < 896);
#pragma unroll
    for (int m = 0; m < 2; ++m) {
        const int rowl = wr * 32 + m * 16 + s * 4;
#pragma unroll
        for (int n = 0; n < 4; ++n) {
            const int col = wc * 64 + n * 16 + lrow;
            const float bv = bvec[c0 + col];
            const int chunk = col >> 3, cb = col & 7;
#pragma unroll
            for (int r = 0; r < 4; ++r) {
                float v = acc[m][n][r] + bv;
                if (doNorm) v *= nrmv[m][r];
                const int row = rowl + r;
                Pst[row * 128 + ((chunk ^ (row & 7)) * 8 + cb)] = f2bf(v);
            }
        }
    }
    __syncthreads();

    const int ch = tid & 15;
#pragma unroll
    for (int rr = 0; rr < 4; ++rr) {
        const int rl = rr * 16 + (tid >> 4);
        const int rg = r0 + rl;
        if (rg < N) {
            uint4 v = *(const uint4*)&Pst[rl * 128 + ((ch ^ (rl & 7)) * 8)];
            *(uint4*)(P + (size_t)rg * NCOLS + c0 + ch * 8) = v;
        }
    }
}

// ---- histogram: edge count + entry count per dst ----
__global__ void k_hist(const int* __restrict__ dst, const float* __restrict__ degrees,
                       int* __restrict__ counts_e, int* __restrict__ counts_n, int E) {
    int e = blockIdx.x * blockDim.x + threadIdx.x;
    if (e >= E) return;
    unsigned zm = 0;
#pragma unroll
    for (int i = 0; i < 6; ++i)
        if (!(degrees[(size_t)e * 6 + i] > 0.f)) zm |= (1u << i);
    const int d = dst[e];
    atomicAdd(&counts_e[d], 1);
    int ne = ne_of(zm);
    if (ne) atomicAdd(&counts_n[d], ne);
}

// ---- 3-phase exclusive scan ----
__global__ void __launch_bounds__(256) k_scan_a(const int* __restrict__ counts,
                                                int* __restrict__ offs,
                                                int* __restrict__ bsum, int N) {
    __shared__ int sm[256];
    int tid = threadIdx.x;
    int i = blockIdx.x * 256 + tid;
    int v = (i < N) ? counts[i] : 0;
    sm[tid] = v;
    __syncthreads();
#pragma unroll
    for (int st = 1; st < 256; st <<= 1) {
        int t = (tid >= st) ? sm[tid - st] : 0;
        __syncthreads();
        sm[tid] += t;
        __syncthreads();
    }
    if (i < N) offs[i] = sm[tid] - v;
    if (tid == 255) bsum[blockIdx.x] = sm[255];
}

__global__ void __launch_bounds__(256) k_scan_b(int* __restrict__ bsum, int NB) {
    __shared__ int sm[256];
    int tid = threadIdx.x;
    int v = (tid < NB) ? bsum[tid] : 0;
    sm[tid] = v;
    __syncthreads();
#pragma unroll
    for (int st = 1; st < 256; st <<= 1) {
        int t = (tid >= st) ? sm[tid - st] : 0;
        __syncthreads();
        sm[tid] += t;
        __syncthreads();
    }
    if (tid < NB) bsum[tid] = sm[tid] - v;
}

__global__ void k_scan_c(int* __restrict__ offs, const int* __restrict__ bsum,
                         int* __restrict__ cursor, int N) {
    int i = blockIdx.x * 256 + threadIdx.x;
    if (i >= N) return;
    int o = offs[i] + bsum[blockIdx.x];
    offs[i] = o;
    cursor[i] = o;
}

// ---- scatter: edge-CSR (pedge) + entry-CSR (entries), no float atomics ----
__global__ void k_scatter(const int* __restrict__ src, const int* __restrict__ dst,
                          const float* __restrict__ degrees,
                          int* __restrict__ cursor_e, uint2* __restrict__ pedge,
                          int* __restrict__ cursor_n, unsigned* __restrict__ entries, int E) {
    int e = blockIdx.x * blockDim.x + threadIdx.x;
    if (e >= E) return;
    const int d = dst[e];
    const int s = src[e];
    unsigned zm = 0, pk = 0;
#pragma unroll
    for (int i = 0; i < 6; ++i) {
        float df = degrees[(size_t)e * 6 + i];
        if (!(df > 0.f)) zm |= (1u << i);
        pk |= ((unsigned)df) << (4 * i);
    }
    const int z = __popc(zm);
    const int ne = ne_of(zm);

    int se = atomicAdd(&cursor_e[d], 1);
    pedge[se] = make_uint2((unsigned)s, pk);

    if (ne == 0) return;
    int sn = atomicAdd(&cursor_n[d], ne);
    const unsigned base = (unsigned)s * 512u;     // dword index of P row
    if (z <= 2) {
        entries[sn++] = base + 384u;              // + sum-slice
#pragma unroll
        for (int i = 0; i < 6; ++i)
            if ((zm >> i) & 1u) entries[sn++] = (base + i * 64u) | 0x80000000u;  // - zero slices
    } else {
#pragma unroll
        for (int i = 0; i < 6; ++i)
            if (!((zm >> i) & 1u)) entries[sn++] = base + i * 64u;               // + nonzero slices
    }
}

// ---- aggregate v6: lane-parallel base phase + scalar-addressed gather phase ----
__global__ void __launch_bounds__(256) k_aggregate(
    const unsigned* __restrict__ Pd,
    const int* __restrict__ eoffs, const int* __restrict__ ecnts,
    const uint2* __restrict__ pedge,
    const int* __restrict__ noffs, const int* __restrict__ ncnts,
    const unsigned* __restrict__ entries,
    const float* __restrict__ norm, const float* __restrict__ W_edge,
    const float* __restrict__ bias, float* __restrict__ out, int N)
{
    const int wid = __builtin_amdgcn_readfirstlane(threadIdx.x >> 6);
    const int n = blockIdx.x * 4 + wid;
    if (n >= N) return;
    const int lane = threadIdx.x & 63;

    float2 w[6];
#pragma unroll
    for (int i = 0; i < 6; ++i) w[i] = *(const float2*)(W_edge + i * OUT_F + lane * 2);

    // ---- phase A: base term from edge-CSR, lane-parallel ----
    const int ebeg = eoffs[n];
    const int ecnt = ecnts[n];
    float Swd[6] = {0.f, 0.f, 0.f, 0.f, 0.f, 0.f};
    for (int p0 = 0; p0 < ecnt; p0 += 64) {
        uint2 pe = (p0 + lane < ecnt) ? pedge[ebeg + p0 + lane] : make_uint2(0u, 0u);
        const float nr = (pe.y != 0u) ? norm[pe.x] : 0.f;
#pragma unroll
        for (int i = 0; i < 6; ++i)
            Swd[i] = fmaf(nr, (float)((pe.y >> (4 * i)) & 15u), Swd[i]);
    }
    float b0 = 0.f, b1 = 0.f;
#pragma unroll
    for (int i = 0; i < 6; ++i) {
        float v = Swd[i];
#pragma unroll
        for (int st = 1; st < 64; st <<= 1) v += __shfl_xor(v, st);
        b0 = fmaf(v, w[i].x, b0);
        b1 = fmaf(v, w[i].y, b1);
    }

    // ---- phase B: scalar-addressed gathers (entry words are wave-uniform) ----
    float g0 = 0.f, g1 = 0.f;
    const int nbeg = __builtin_amdgcn_readfirstlane(noffs[n]);
    const int ncnt = __builtin_amdgcn_readfirstlane(ncnts[n]);
    const int nend = nbeg + ncnt;
    int j = nbeg;
    for (; j + 8 <= nend; j += 8) {
        unsigned ev[8], uv[8];
#pragma unroll
        for (int q = 0; q < 8; ++q)
            ev[q] = __builtin_amdgcn_readfirstlane(entries[j + q]);
#pragma unroll
        for (int q = 0; q < 8; ++q)
            uv[q] = Pd[(ev[q] & 0x7fffffffu) + lane];   // SGPR base + lane*4 voffset
#pragma unroll
        for (int q = 0; q < 8; ++q) {
            float sg = __uint_as_float(0x3f800000u | (ev[q] & 0x80000000u));
            g0 = fmaf(sg, bf_lo(uv[q]), g0);
            g1 = fmaf(sg, bf_hi(uv[q]), g1);
        }
    }
    for (; j < nend; ++j) {
        unsigned e0 = __builtin_amdgcn_readfirstlane(entries[j]);
        unsigned u0 = Pd[(e0 & 0x7fffffffu) + lane];
        float sg = __uint_as_float(0x3f800000u | (e0 & 0x80000000u));
        g0 = fmaf(sg, bf_lo(u0), g0);
        g1 = fmaf(sg, bf_hi(u0), g1);
    }

    // ---- fused epilogue: relu(accum*norm + self + bias) ----
    const unsigned us = Pd[(size_t)n * 512 + 448 + lane];
    const float nd = norm[n];
    const float2 bv = *(const float2*)(bias + lane * 2);
    float2 o;
    o.x = fmaxf((g0 + b0) * nd + bf_lo(us) + bv.x, 0.f);
    o.y = fmaxf((g1 + b1) * nd + bf_hi(us) + bv.y, 0.f);
    *(float2*)(out + (size_t)n * OUT_F + lane * 2) = o;
}

extern "C" void kernel_launch(void* const* d_in, const int* in_sizes, int n_in,
                              void* d_out, int out_size, void* d_ws, size_t ws_size,
                              hipStream_t stream)
{
    const float* h       = (const float*)d_in[0];
    const float* degrees = (const float*)d_in[1];
    const float* norm    = (const float*)d_in[2];
    const int*   src     = (const int*)d_in[3];
    const int*   dst     = (const int*)d_in[4];
    const float* W_self  = (const float*)d_in[5];
    const float* b_self  = (const float*)d_in[6];
    const float* W_node  = (const float*)d_in[7];
    const float* b_node  = (const float*)d_in[8];
    const float* W_edge  = (const float*)d_in[9];
    const float* bias    = (const float*)d_in[10];
    float* out = (float*)d_out;

    const int N = in_sizes[2];   // norm [N,1]
    const int E = in_sizes[3];   // src [E]
    const int NB = (N + 255) / 256;

    char* ws = (char*)d_ws;
    size_t off = 0;
    auto alloc = [&](size_t sz) { size_t o = off; off = (off + sz + 255) & ~(size_t)255; return o; };
    unsigned short* P        = (unsigned short*)(ws + alloc((size_t)N * NCOLS * 2)); // 102.4 MB
    char*           hbRegion = (ws + alloc((size_t)N * IN_F * 2));                   // 25.6 MB
    unsigned short* Wt       = (unsigned short*)(ws + alloc((size_t)NCOLS * IN_F * 2));
    float*          bvec     = (float*)(ws + alloc(NCOLS * 4));
    int*            counts_e = (int*)(ws + alloc((size_t)N * 4));
    int*            offs_e   = (int*)(ws + alloc((size_t)N * 4));
    int*            cursor_e = (int*)(ws + alloc((size_t)N * 4));
    int*            counts_n = (int*)(ws + alloc((size_t)N * 4));
    int*            offs_n   = (int*)(ws + alloc((size_t)N * 4));
    int*            cursor_n = (int*)(ws + alloc((size_t)N * 4));
    int*            bsum     = (int*)(ws + alloc((size_t)NB * 4));

    // pedge (6.4 MB) + entries (<=9.6 MB) alias the hb region: hb is dead after
    // k_gemm, and the stream order conv_h -> gemm -> scatter -> aggregate is fixed.
    unsigned short* hb      = (unsigned short*)hbRegion;
    uint2*          pedge   = (uint2*)hbRegion;
    unsigned*       entries = (unsigned*)(hbRegion + ((size_t)E * 8 + 255 & ~(size_t)255));

    hipMemsetAsync(counts_e, 0, (size_t)N * 4, stream);
    hipMemsetAsync(counts_n, 0, (size_t)N * 4, stream);

    int t8 = N * (IN_F / 8);
    k_conv_h<<<(t8 + 255) / 256, 256, 0, stream>>>(h, hb, t8);

    int tw = IN_F * NCOLS;
    k_conv_w<<<(tw + 255) / 256, 256, 0, stream>>>(W_node, W_self, b_node, b_self, Wt, bvec, tw);

    const int R  = (N + BM - 1) / BM;
    const int RP = (R + 7) / 8;
    k_gemm<<<RP * 8 * 8, 256, 0, stream>>>(hb, Wt, bvec, norm, P, N, RP);

    k_hist<<<(E + 255) / 256, 256, 0, stream>>>(dst, degrees, counts_e, counts_n, E);
    k_scan_a<<<NB, 256, 0, stream>>>(counts_e, offs_e, bsum, N);
    k_scan_b<<<1, 256, 0, stream>>>(bsum, NB);
    k_scan_c<<<NB, 256, 0, stream>>>(offs_e, bsum, cursor_e, N);
    k_scan_a<<<NB, 256, 0, stream>>>(counts_n, offs_n, bsum, N);
    k_scan_b<<<1, 256, 0, stream>>>(bsum, NB);
    k_scan_c<<<NB, 256, 0, stream>>>(offs_n, bsum, cursor_n, N);

    k_scatter<<<(E + 255) / 256, 256, 0, stream>>>(src, dst, degrees,
                                                   cursor_e, pedge, cursor_n, entries, E);

    k_aggregate<<<(N + 3) / 4, 256, 0, stream>>>((const unsigned*)P,
                                                 offs_e, counts_e, pedge,
                                                 offs_n, counts_n, entries,
                                                 norm, W_edge, bias, out, N);
}

// Round 10
// 230.507 us; speedup vs baseline: 1.7928x; 1.4877x over previous
//
#include <hip/hip_runtime.h>
#include <stdint.h>

#define IN_F 256
#define OUT_F 128
#define NCOLS 1024   // 768 slices + 128 sum-slice + 128 self (all bf16)
#define BM 64
#define BN 128
#define BK 32

using bf16x8 = __attribute__((ext_vector_type(8))) __bf16;
using f32x4  = __attribute__((ext_vector_type(4))) float;

static __device__ __forceinline__ unsigned short f2bf(float f) {
    unsigned u = __float_as_uint(f);
    u = u + 0x7fffu + ((u >> 16) & 1u);   // RNE
    return (unsigned short)(u >> 16);
}
static __device__ __forceinline__ float bf_lo(unsigned u) { return __uint_as_float(u << 16); }
static __device__ __forceinline__ float bf_hi(unsigned u) { return __uint_as_float(u & 0xffff0000u); }

static __device__ __forceinline__ void async_load16(const void* g, void* l) {
    __builtin_amdgcn_global_load_lds(
        (__attribute__((address_space(1))) void*)g,
        (__attribute__((address_space(3))) void*)l,
        16, 0, 0);
}

// ---- h (f32) -> bf16 ----
__global__ void k_conv_h(const float* __restrict__ h, unsigned short* __restrict__ hb, int total8) {
    int i = blockIdx.x * blockDim.x + threadIdx.x;
    if (i >= total8) return;
    const float4* src = ((const float4*)h) + (size_t)i * 2;
    float4 a = src[0], b = src[1];
    union { unsigned short us[8]; uint4 v; } u;
    u.us[0] = f2bf(a.x); u.us[1] = f2bf(a.y); u.us[2] = f2bf(a.z); u.us[3] = f2bf(a.w);
    u.us[4] = f2bf(b.x); u.us[5] = f2bf(b.y); u.us[6] = f2bf(b.z); u.us[7] = f2bf(b.w);
    ((uint4*)hb)[i] = u.v;
}

// ---- Wt[1024][256] = [W_node | sum(slices) | W_self]^T bf16; bvec[1024] ----
__global__ void k_conv_w(const float* __restrict__ Wn, const float* __restrict__ Ws,
                         const float* __restrict__ bn, const float* __restrict__ bs,
                         unsigned short* __restrict__ Wt, float* __restrict__ bvec, int total) {
    int i = blockIdx.x * blockDim.x + threadIdx.x;   // i = k*1024 + c
    if (i >= total) return;
    int k = i >> 10, c = i & 1023;
    float v;
    if (c < 768) {
        v = Wn[(size_t)k * 768 + c];
    } else if (c < 896) {
        int j = c - 768; v = 0.f;
#pragma unroll
        for (int s = 0; s < 6; ++s) v += Wn[(size_t)k * 768 + s * 128 + j];
    } else {
        v = Ws[(size_t)k * 128 + (c - 896)];
    }
    Wt[(size_t)c * IN_F + k] = f2bf(v);

    if (i < NCOLS) {
        float b;
        if (i < 768) b = bn[i];
        else if (i < 896) {
            int j = i - 768; b = 0.f;
#pragma unroll
            for (int s = 0; s < 6; ++s) b += bn[s * 128 + j];
        } else b = bs[i - 896];
        bvec[i] = b;
    }
}

// ---- GEMM (R5-proven): XCD-chunked swizzle + LDS-staged coalesced C-store ----
__global__ void __launch_bounds__(256) k_gemm(
    const unsigned short* __restrict__ hb,
    const unsigned short* __restrict__ Wt,
    const float* __restrict__ bvec,
    const float* __restrict__ norm,
    unsigned short* __restrict__ P, int N, int rowsPerXcd)
{
    __shared__ char lds[(BM + BN) * BK * 2];       // 12 KB (A 4 KB, B 8 KB)
    __shared__ unsigned short Pst[BM * BN];        // 16 KB store staging
    char* Ab = lds;
    char* Bb = lds + BM * BK * 2;

    const int f  = blockIdx.x;
    const int xc = f & 7;
    const int j  = f >> 3;
    const int rs = xc * rowsPerXcd + (j >> 3);
    const int ct = j & 7;
    const int r0 = rs * BM;
    if (r0 >= N) return;
    const int c0 = ct * BN;

    const int tid = threadIdx.x;
    const int wid = tid >> 6, lane = tid & 63;
    const int lrow = lane & 15, s = lane >> 4;
    const int wr = wid >> 1, wc = wid & 1;

    const int arow = tid >> 2;
    const int achunk = (tid & 3) ^ ((arow >> 1) & 3);
    int agrow = r0 + arow; if (agrow >= N) agrow = N - 1;
    const unsigned short* aseg = hb + (size_t)agrow * IN_F + achunk * 8;

    const int bcol0 = tid >> 2;
    const int bchunk0 = (tid & 3) ^ ((bcol0 >> 1) & 3);
    const unsigned short* bseg0 = Wt + (size_t)(c0 + bcol0) * IN_F + bchunk0 * 8;
    const int idx1 = tid + 256;
    const int bcol1 = idx1 >> 2;
    const int bchunk1 = (idx1 & 3) ^ ((bcol1 >> 1) & 3);
    const unsigned short* bseg1 = Wt + (size_t)(c0 + bcol1) * IN_F + bchunk1 * 8;

    int a_off[2], b_off[4];
#pragma unroll
    for (int m = 0; m < 2; ++m) {
        int rl = wr * 32 + m * 16 + lrow;
        a_off[m] = rl * 64 + ((s ^ ((rl >> 1) & 3)) << 4);
    }
#pragma unroll
    for (int n = 0; n < 4; ++n) {
        int cl = wc * 64 + n * 16 + lrow;
        b_off[n] = cl * 64 + ((s ^ ((cl >> 1) & 3)) << 4);
    }

    float nrmv[2][4];
#pragma unroll
    for (int m = 0; m < 2; ++m)
#pragma unroll
        for (int r = 0; r < 4; ++r) {
            int rg = r0 + wr * 32 + m * 16 + s * 4 + r;
            nrmv[m][r] = norm[rg < N ? rg : N - 1];
        }

    f32x4 acc[2][4] = {};

    for (int kk = 0; kk < IN_F / BK; ++kk) {
        async_load16(aseg + kk * BK, Ab + tid * 16);
        async_load16(bseg0 + kk * BK, Bb + tid * 16);
        async_load16(bseg1 + kk * BK, Bb + (tid + 256) * 16);
        __syncthreads();

        bf16x8 af[2], bfv[4];
#pragma unroll
        for (int m = 0; m < 2; ++m) af[m] = *(const bf16x8*)(Ab + a_off[m]);
#pragma unroll
        for (int n = 0; n < 4; ++n) bfv[n] = *(const bf16x8*)(Bb + b_off[n]);
#pragma unroll
        for (int m = 0; m < 2; ++m)
#pragma unroll
            for (int n = 0; n < 4; ++n)
                acc[m][n] = __builtin_amdgcn_mfma_f32_16x16x32_bf16(af[m], bfv[n], acc[m][n], 0, 0, 0);
        __syncthreads();
    }

    const bool doNorm = (c0 < 896);
#pragma unroll
    for (int m = 0; m < 2; ++m) {
        const int rowl = wr * 32 + m * 16 + s * 4;
#pragma unroll
        for (int n = 0; n < 4; ++n) {
            const int col = wc * 64 + n * 16 + lrow;
            const float bv = bvec[c0 + col];
            const int chunk = col >> 3, cb = col & 7;
#pragma unroll
            for (int r = 0; r < 4; ++r) {
                float v = acc[m][n][r] + bv;
                if (doNorm) v *= nrmv[m][r];
                const int row = rowl + r;
                Pst[row * 128 + ((chunk ^ (row & 7)) * 8 + cb)] = f2bf(v);
            }
        }
    }
    __syncthreads();

    const int ch = tid & 15;
#pragma unroll
    for (int rr = 0; rr < 4; ++rr) {
        const int rl = rr * 16 + (tid >> 4);
        const int rg = r0 + rl;
        if (rg < N) {
            uint4 v = *(const uint4*)&Pst[rl * 128 + ((ch ^ (rl & 7)) * 8)];
            *(uint4*)(P + (size_t)rg * NCOLS + c0 + ch * 8) = v;
        }
    }
}

// ---- histogram over dst (edge counts) ----
__global__ void k_hist(const int* __restrict__ dst, int* __restrict__ counts, int E) {
    int e = blockIdx.x * blockDim.x + threadIdx.x;
    if (e < E) atomicAdd(&counts[dst[e]], 1);
}

// ---- 3-phase exclusive scan over counts[N] ----
__global__ void __launch_bounds__(256) k_scan_a(const int* __restrict__ counts,
                                                int* __restrict__ offs,
                                                int* __restrict__ bsum, int N) {
    __shared__ int sm[256];
    int tid = threadIdx.x;
    int i = blockIdx.x * 256 + tid;
    int v = (i < N) ? counts[i] : 0;
    sm[tid] = v;
    __syncthreads();
#pragma unroll
    for (int st = 1; st < 256; st <<= 1) {
        int t = (tid >= st) ? sm[tid - st] : 0;
        __syncthreads();
        sm[tid] += t;
        __syncthreads();
    }
    if (i < N) offs[i] = sm[tid] - v;
    if (tid == 255) bsum[blockIdx.x] = sm[255];
}

__global__ void __launch_bounds__(256) k_scan_b(int* __restrict__ bsum, int NB) {
    __shared__ int sm[256];
    int tid = threadIdx.x;
    int v = (tid < NB) ? bsum[tid] : 0;
    sm[tid] = v;
    __syncthreads();
#pragma unroll
    for (int st = 1; st < 256; st <<= 1) {
        int t = (tid >= st) ? sm[tid - st] : 0;
        __syncthreads();
        sm[tid] += t;
        __syncthreads();
    }
    if (tid < NB) bsum[tid] = sm[tid] - v;
}

__global__ void k_scan_c(int* __restrict__ offs, const int* __restrict__ bsum,
                         int* __restrict__ cursor, int N) {
    int i = blockIdx.x * 256 + threadIdx.x;
    if (i >= N) return;
    int o = offs[i] + bsum[blockIdx.x];
    offs[i] = o;
    cursor[i] = o;
}

// ---- scatter edges into CSR order: pedge[slot] = {src, packed degs} ----
__global__ void k_scatter(const int* __restrict__ src, const int* __restrict__ dst,
                          const float* __restrict__ degrees,
                          int* __restrict__ cursor, uint2* __restrict__ pedge, int E) {
    int e = blockIdx.x * blockDim.x + threadIdx.x;
    if (e >= E) return;
    int d = dst[e];
    int slot = atomicAdd(&cursor[d], 1);
    unsigned pk = 0;
#pragma unroll
    for (int i = 0; i < 6; ++i) {
        float df = degrees[(size_t)e * 6 + i];
        pk |= ((unsigned)df) << (4 * i);
    }
    pedge[slot] = make_uint2((unsigned)src[e], pk);
}

// ---- aggregate: R5 structure + scalar-addressed (SGPR) phase-B gathers ----
__global__ void __launch_bounds__(256) k_aggregate(
    const unsigned* __restrict__ Pd,
    const int* __restrict__ row_start, const int* __restrict__ counts,
    const uint2* __restrict__ pedge,
    const float* __restrict__ norm, const float* __restrict__ W_edge,
    const float* __restrict__ bias, float* __restrict__ out, int N)
{
    __shared__ unsigned EL[4][192];
    const int wid = threadIdx.x >> 6;
    const int n = blockIdx.x * 4 + wid;
    if (n >= N) return;
    const int lane = threadIdx.x & 63;
    unsigned* el = EL[wid];

    float2 w[6];
#pragma unroll
    for (int i = 0; i < 6; ++i) w[i] = *(const float2*)(W_edge + i * OUT_F + lane * 2);

    const int beg = row_start[n];
    const int end = beg + counts[n];

    float Swd[6] = {0.f, 0.f, 0.f, 0.f, 0.f, 0.f};
    float g0 = 0.f, g1 = 0.f;

    for (int p0 = beg; p0 < end; p0 += 64) {
        // ---- phase A: lane t handles edge p0+t ----
        const int t = p0 + lane;
        uint2 pe = (t < end) ? pedge[t] : make_uint2(0u, 0u);
        const unsigned dp = pe.y;
        const float nr = (dp != 0u) ? norm[pe.x] : 0.f;

        unsigned zm = 0;
#pragma unroll
        for (int i = 0; i < 6; ++i) {
            int d = (dp >> (4 * i)) & 15;
            if (d == 0) zm |= (1u << i);
            Swd[i] += nr * (float)d;
        }
        const int z = __popc(zm);
        const int ne = (dp == 0u) ? 0 : ((z <= 2) ? (1 + z) : (6 - z));

        // inclusive wave prefix-sum of ne
        int x = ne;
#pragma unroll
        for (int st = 1; st < 64; st <<= 1) {
            int v = __shfl_up(x, st);
            if (lane >= st) x += v;
        }
        const int excl = x - ne;
        const int total = __shfl(x, 63);

        if (ne) {
            const unsigned base = pe.x * 512u;       // dword index of P row
            int wp = excl;
            if (z <= 2) {
                el[wp++] = base + 384u;              // + sum-slice
#pragma unroll
                for (int i = 0; i < 6; ++i)
                    if ((zm >> i) & 1u) el[wp++] = (base + i * 64u) | 0x80000000u;  // - zero slices
            } else {
#pragma unroll
                for (int i = 0; i < 6; ++i)
                    if (!((zm >> i) & 1u)) el[wp++] = base + i * 64u;               // + nonzero slices
            }
        }
        asm volatile("s_waitcnt lgkmcnt(0)" ::: "memory");

        // ---- phase B: entries are wave-uniform -> SGPR base addressing, 8-deep MLP ----
        int j = 0;
        for (; j + 8 <= total; j += 8) {
            unsigned ev[8], uv[8];
#pragma unroll
            for (int q = 0; q < 8; ++q)
                ev[q] = __builtin_amdgcn_readfirstlane(el[j + q]);
#pragma unroll
            for (int q = 0; q < 8; ++q)
                uv[q] = Pd[(ev[q] & 0x7fffffffu) + lane];   // SGPR base + lane voffset
#pragma unroll
            for (int q = 0; q < 8; ++q) {
                float sg = __uint_as_float(0x3f800000u | (ev[q] & 0x80000000u));
                g0 = fmaf(sg, bf_lo(uv[q]), g0);
                g1 = fmaf(sg, bf_hi(uv[q]), g1);
            }
        }
        for (; j < total; ++j) {
            unsigned e0 = __builtin_amdgcn_readfirstlane(el[j]);
            unsigned u0 = Pd[(e0 & 0x7fffffffu) + lane];
            float sg = __uint_as_float(0x3f800000u | (e0 & 0x80000000u));
            g0 = fmaf(sg, bf_lo(u0), g0);
            g1 = fmaf(sg, bf_hi(u0), g1);
        }
    }

    // ---- reduce Swd across the wave, fold base term ----
    float b0 = 0.f, b1 = 0.f;
#pragma unroll
    for (int i = 0; i < 6; ++i) {
        float v = Swd[i];
#pragma unroll
        for (int st = 1; st < 64; st <<= 1) v += __shfl_xor(v, st);
        b0 = fmaf(v, w[i].x, b0);
        b1 = fmaf(v, w[i].y, b1);
    }

    // ---- fused epilogue: relu(accum*norm + self + bias) ----
    const unsigned us = Pd[(size_t)n * 512 + 448 + lane];
    const float nd = norm[n];
    const float2 bv = *(const float2*)(bias + lane * 2);
    float2 o;
    o.x = fmaxf((g0 + b0) * nd + bf_lo(us) + bv.x, 0.f);
    o.y = fmaxf((g1 + b1) * nd + bf_hi(us) + bv.y, 0.f);
    *(float2*)(out + (size_t)n * OUT_F + lane * 2) = o;
}

extern "C" void kernel_launch(void* const* d_in, const int* in_sizes, int n_in,
                              void* d_out, int out_size, void* d_ws, size_t ws_size,
                              hipStream_t stream)
{
    const float* h       = (const float*)d_in[0];
    const float* degrees = (const float*)d_in[1];
    const float* norm    = (const float*)d_in[2];
    const int*   src     = (const int*)d_in[3];
    const int*   dst     = (const int*)d_in[4];
    const float* W_self  = (const float*)d_in[5];
    const float* b_self  = (const float*)d_in[6];
    const float* W_node  = (const float*)d_in[7];
    const float* b_node  = (const float*)d_in[8];
    const float* W_edge  = (const float*)d_in[9];
    const float* bias    = (const float*)d_in[10];
    float* out = (float*)d_out;

    const int N = in_sizes[2];   // norm [N,1]
    const int E = in_sizes[3];   // src [E]
    const int NB = (N + 255) / 256;

    char* ws = (char*)d_ws;
    size_t off = 0;
    auto alloc = [&](size_t sz) { size_t o = off; off = (off + sz + 255) & ~(size_t)255; return o; };
    unsigned short* P      = (unsigned short*)(ws + alloc((size_t)N * NCOLS * 2)); // 102.4 MB
    unsigned short* hb     = (unsigned short*)(ws + alloc((size_t)N * IN_F * 2));  // 25.6 MB
    unsigned short* Wt     = (unsigned short*)(ws + alloc((size_t)NCOLS * IN_F * 2));
    float*          bvec   = (float*)(ws + alloc(NCOLS * 4));
    int*            counts = (int*)(ws + alloc((size_t)N * 4));
    int*            offs   = (int*)(ws + alloc((size_t)N * 4));
    int*            cursor = (int*)(ws + alloc((size_t)N * 4));
    int*            bsum   = (int*)(ws + alloc((size_t)NB * 4));
    uint2*          pedge  = (uint2*)(ws + alloc((size_t)E * 8));                  // 6.4 MB

    hipMemsetAsync(counts, 0, (size_t)N * 4, stream);

    int t8 = N * (IN_F / 8);
    k_conv_h<<<(t8 + 255) / 256, 256, 0, stream>>>(h, hb, t8);

    int tw = IN_F * NCOLS;
    k_conv_w<<<(tw + 255) / 256, 256, 0, stream>>>(W_node, W_self, b_node, b_self, Wt, bvec, tw);

    const int R  = (N + BM - 1) / BM;
    const int RP = (R + 7) / 8;
    k_gemm<<<RP * 8 * 8, 256, 0, stream>>>(hb, Wt, bvec, norm, P, N, RP);

    k_hist<<<(E + 255) / 256, 256, 0, stream>>>(dst, counts, E);
    k_scan_a<<<NB, 256, 0, stream>>>(counts, offs, bsum, N);
    k_scan_b<<<1, 256, 0, stream>>>(bsum, NB);
    k_scan_c<<<NB, 256, 0, stream>>>(offs, bsum, cursor, N);
    k_scatter<<<(E + 255) / 256, 256, 0, stream>>>(src, dst, degrees, cursor, pedge, E);

    k_aggregate<<<(N + 3) / 4, 256, 0, stream>>>((const unsigned*)P, offs, counts, pedge,
                                                 norm, W_edge, bias, out, N);
}

// Round 11
// 210.266 us; speedup vs baseline: 1.9654x; 1.0963x over previous
//
#include <hip/hip_runtime.h>
#include <stdint.h>

#define IN_F 256
#define OUT_F 128
#define NCOLS 1024   // GEMM cols: 768 slices + 128 sum-slice + 128 self
#define PROWB 1152   // P row bytes: 896 fp8 (slices+sum) + 256 bf16 self
#define BM 64
#define BN 128
#define BK 32

using bf16x8 = __attribute__((ext_vector_type(8))) __bf16;
using f32x4  = __attribute__((ext_vector_type(4))) float;
using f32x2  = __attribute__((ext_vector_type(2))) float;

static __device__ __forceinline__ unsigned short f2bf(float f) {
    unsigned u = __float_as_uint(f);
    u = u + 0x7fffu + ((u >> 16) & 1u);   // RNE
    return (unsigned short)(u >> 16);
}
static __device__ __forceinline__ float bf_lo(unsigned u) { return __uint_as_float(u << 16); }
static __device__ __forceinline__ float bf_hi(unsigned u) { return __uint_as_float(u & 0xffff0000u); }

static __device__ __forceinline__ void async_load16(const void* g, void* l) {
    __builtin_amdgcn_global_load_lds(
        (__attribute__((address_space(1))) void*)g,
        (__attribute__((address_space(3))) void*)l,
        16, 0, 0);
}

// ---- h (f32) -> bf16 ----
__global__ void k_conv_h(const float* __restrict__ h, unsigned short* __restrict__ hb, int total8) {
    int i = blockIdx.x * blockDim.x + threadIdx.x;
    if (i >= total8) return;
    const float4* src = ((const float4*)h) + (size_t)i * 2;
    float4 a = src[0], b = src[1];
    union { unsigned short us[8]; uint4 v; } u;
    u.us[0] = f2bf(a.x); u.us[1] = f2bf(a.y); u.us[2] = f2bf(a.z); u.us[3] = f2bf(a.w);
    u.us[4] = f2bf(b.x); u.us[5] = f2bf(b.y); u.us[6] = f2bf(b.z); u.us[7] = f2bf(b.w);
    ((uint4*)hb)[i] = u.v;
}

// ---- Wt[1024][256] = [W_node | sum(slices) | W_self]^T bf16; bvec[1024] ----
__global__ void k_conv_w(const float* __restrict__ Wn, const float* __restrict__ Ws,
                         const float* __restrict__ bn, const float* __restrict__ bs,
                         unsigned short* __restrict__ Wt, float* __restrict__ bvec, int total) {
    int i = blockIdx.x * blockDim.x + threadIdx.x;   // i = k*1024 + c
    if (i >= total) return;
    int k = i >> 10, c = i & 1023;
    float v;
    if (c < 768) {
        v = Wn[(size_t)k * 768 + c];
    } else if (c < 896) {
        int j = c - 768; v = 0.f;
#pragma unroll
        for (int s = 0; s < 6; ++s) v += Wn[(size_t)k * 768 + s * 128 + j];
    } else {
        v = Ws[(size_t)k * 128 + (c - 896)];
    }
    Wt[(size_t)c * IN_F + k] = f2bf(v);

    if (i < NCOLS) {
        float b;
        if (i < 768) b = bn[i];
        else if (i < 896) {
            int j = i - 768; b = 0.f;
#pragma unroll
            for (int s = 0; s < 6; ++s) b += bn[s * 128 + j];
        } else b = bs[i - 896];
        bvec[i] = b;
    }
}

// ---- GEMM: R10 pipeline; epilogue packs fp8 (ct<7) / bf16 self (ct==7) ----
__global__ void __launch_bounds__(256) k_gemm(
    const unsigned short* __restrict__ hb,
    const unsigned short* __restrict__ Wt,
    const float* __restrict__ bvec,
    const float* __restrict__ norm,
    char* __restrict__ PG, int N, int rowsPerXcd)
{
    __shared__ char lds[(BM + BN) * BK * 2];       // 12 KB (A 4 KB, B 8 KB)
    __shared__ unsigned short Pst[BM * BN];        // 16 KB store staging
    char* Ab = lds;
    char* Bb = lds + BM * BK * 2;

    const int f  = blockIdx.x;
    const int xc = f & 7;
    const int j  = f >> 3;
    const int rs = xc * rowsPerXcd + (j >> 3);
    const int ct = j & 7;
    const int r0 = rs * BM;
    if (r0 >= N) return;
    const int c0 = ct * BN;

    const int tid = threadIdx.x;
    const int wid = tid >> 6, lane = tid & 63;
    const int lrow = lane & 15, s = lane >> 4;
    const int wr = wid >> 1, wc = wid & 1;

    const int arow = tid >> 2;
    const int achunk = (tid & 3) ^ ((arow >> 1) & 3);
    int agrow = r0 + arow; if (agrow >= N) agrow = N - 1;
    const unsigned short* aseg = hb + (size_t)agrow * IN_F + achunk * 8;

    const int bcol0 = tid >> 2;
    const int bchunk0 = (tid & 3) ^ ((bcol0 >> 1) & 3);
    const unsigned short* bseg0 = Wt + (size_t)(c0 + bcol0) * IN_F + bchunk0 * 8;
    const int idx1 = tid + 256;
    const int bcol1 = idx1 >> 2;
    const int bchunk1 = (idx1 & 3) ^ ((bcol1 >> 1) & 3);
    const unsigned short* bseg1 = Wt + (size_t)(c0 + bcol1) * IN_F + bchunk1 * 8;

    int a_off[2], b_off[4];
#pragma unroll
    for (int m = 0; m < 2; ++m) {
        int rl = wr * 32 + m * 16 + lrow;
        a_off[m] = rl * 64 + ((s ^ ((rl >> 1) & 3)) << 4);
    }
#pragma unroll
    for (int n = 0; n < 4; ++n) {
        int cl = wc * 64 + n * 16 + lrow;
        b_off[n] = cl * 64 + ((s ^ ((cl >> 1) & 3)) << 4);
    }

    float nrmv[2][4];
#pragma unroll
    for (int m = 0; m < 2; ++m)
#pragma unroll
        for (int r = 0; r < 4; ++r) {
            int rg = r0 + wr * 32 + m * 16 + s * 4 + r;
            nrmv[m][r] = norm[rg < N ? rg : N - 1];
        }

    f32x4 acc[2][4] = {};

    for (int kk = 0; kk < IN_F / BK; ++kk) {
        async_load16(aseg + kk * BK, Ab + tid * 16);
        async_load16(bseg0 + kk * BK, Bb + tid * 16);
        async_load16(bseg1 + kk * BK, Bb + (tid + 256) * 16);
        __syncthreads();

        bf16x8 af[2], bfv[4];
#pragma unroll
        for (int m = 0; m < 2; ++m) af[m] = *(const bf16x8*)(Ab + a_off[m]);
#pragma unroll
        for (int n = 0; n < 4; ++n) bfv[n] = *(const bf16x8*)(Bb + b_off[n]);
#pragma unroll
        for (int m = 0; m < 2; ++m)
#pragma unroll
            for (int n = 0; n < 4; ++n)
                acc[m][n] = __builtin_amdgcn_mfma_f32_16x16x32_bf16(af[m], bfv[n], acc[m][n], 0, 0, 0);
        __syncthreads();
    }

    float bvn[4];
#pragma unroll
    for (int n = 0; n < 4; ++n) bvn[n] = bvec[c0 + wc * 64 + n * 16 + lrow];

    if (ct < 7) {
        // ---- fp8 tile (slices 0-5 and sum), norm-prescaled ----
        char* PstB = (char*)Pst;
#pragma unroll
        for (int m = 0; m < 2; ++m) {
            const int rowl = wr * 32 + m * 16 + s * 4;
#pragma unroll
            for (int n = 0; n < 4; ++n) {
#pragma unroll
                for (int r = 0; r < 4; ++r) {
                    float v = (acc[m][n][r] + bvn[n]) * nrmv[m][r];
                    int pk = __builtin_amdgcn_cvt_pk_fp8_f32(v, v, 0, false);
                    const int row = rowl + r;
                    PstB[row * 128 + (((wc * 4 + n) ^ (row & 7)) * 16) + lrow] = (char)pk;
                }
            }
        }
        __syncthreads();
#pragma unroll
        for (int it = 0; it < 2; ++it) {
            const int idx = it * 256 + tid;
            const int rl = idx >> 3, ch = idx & 7;
            const int rg = r0 + rl;
            if (rg < N) {
                uint4 v = *(const uint4*)&PstB[rl * 128 + ((ch ^ (rl & 7)) * 16)];
                *(uint4*)(PG + (size_t)rg * PROWB + ct * 128 + ch * 16) = v;
            }
        }
    } else {
        // ---- bf16 self tile (no norm) ----
#pragma unroll
        for (int m = 0; m < 2; ++m) {
            const int rowl = wr * 32 + m * 16 + s * 4;
#pragma unroll
            for (int n = 0; n < 4; ++n) {
                const int col = wc * 64 + n * 16 + lrow;
                const int chunk = col >> 3, cb = col & 7;
#pragma unroll
                for (int r = 0; r < 4; ++r) {
                    float v = acc[m][n][r] + bvn[n];
                    const int row = rowl + r;
                    Pst[row * 128 + ((chunk ^ (row & 7)) * 8 + cb)] = f2bf(v);
                }
            }
        }
        __syncthreads();
        const int ch = tid & 15;
#pragma unroll
        for (int rr = 0; rr < 4; ++rr) {
            const int rl = rr * 16 + (tid >> 4);
            const int rg = r0 + rl;
            if (rg < N) {
                uint4 v = *(const uint4*)&Pst[rl * 128 + ((ch ^ (rl & 7)) * 8)];
                *(uint4*)(PG + (size_t)rg * PROWB + 896 + ch * 16) = v;
            }
        }
    }
}

// ---- histogram over dst (edge counts) ----
__global__ void k_hist(const int* __restrict__ dst, int* __restrict__ counts, int E) {
    int e = blockIdx.x * blockDim.x + threadIdx.x;
    if (e < E) atomicAdd(&counts[dst[e]], 1);
}

// ---- 3-phase exclusive scan over counts[N] ----
__global__ void __launch_bounds__(256) k_scan_a(const int* __restrict__ counts,
                                                int* __restrict__ offs,
                                                int* __restrict__ bsum, int N) {
    __shared__ int sm[256];
    int tid = threadIdx.x;
    int i = blockIdx.x * 256 + tid;
    int v = (i < N) ? counts[i] : 0;
    sm[tid] = v;
    __syncthreads();
#pragma unroll
    for (int st = 1; st < 256; st <<= 1) {
        int t = (tid >= st) ? sm[tid - st] : 0;
        __syncthreads();
        sm[tid] += t;
        __syncthreads();
    }
    if (i < N) offs[i] = sm[tid] - v;
    if (tid == 255) bsum[blockIdx.x] = sm[255];
}

__global__ void __launch_bounds__(256) k_scan_b(int* __restrict__ bsum, int NB) {
    __shared__ int sm[256];
    int tid = threadIdx.x;
    int v = (tid < NB) ? bsum[tid] : 0;
    sm[tid] = v;
    __syncthreads();
#pragma unroll
    for (int st = 1; st < 256; st <<= 1) {
        int t = (tid >= st) ? sm[tid - st] : 0;
        __syncthreads();
        sm[tid] += t;
        __syncthreads();
    }
    if (tid < NB) bsum[tid] = sm[tid] - v;
}

__global__ void k_scan_c(int* __restrict__ offs, const int* __restrict__ bsum,
                         int* __restrict__ cursor, int N) {
    int i = blockIdx.x * 256 + threadIdx.x;
    if (i >= N) return;
    int o = offs[i] + bsum[blockIdx.x];
    offs[i] = o;
    cursor[i] = o;
}

// ---- scatter edges into CSR order: pedge[slot] = {src, packed degs} ----
__global__ void k_scatter(const int* __restrict__ src, const int* __restrict__ dst,
                          const float* __restrict__ degrees,
                          int* __restrict__ cursor, uint2* __restrict__ pedge, int E) {
    int e = blockIdx.x * blockDim.x + threadIdx.x;
    if (e >= E) return;
    int d = dst[e];
    int slot = atomicAdd(&cursor[d], 1);
    unsigned pk = 0;
#pragma unroll
    for (int i = 0; i < 6; ++i) {
        float df = degrees[(size_t)e * 6 + i];
        pk |= ((unsigned)df) << (4 * i);
    }
    pedge[slot] = make_uint2((unsigned)src[e], pk);
}

// ---- aggregate: R10 structure, fp8 payload (byte-offset entries) ----
__global__ void __launch_bounds__(256) k_aggregate(
    const char* __restrict__ PG,
    const int* __restrict__ row_start, const int* __restrict__ counts,
    const uint2* __restrict__ pedge,
    const float* __restrict__ norm, const float* __restrict__ W_edge,
    const float* __restrict__ bias, float* __restrict__ out, int N)
{
    __shared__ unsigned EL[4][192];
    const int wid = threadIdx.x >> 6;
    const int n = blockIdx.x * 4 + wid;
    if (n >= N) return;
    const int lane = threadIdx.x & 63;
    const int l2 = lane * 2;
    unsigned* el = EL[wid];

    float2 w[6];
#pragma unroll
    for (int i = 0; i < 6; ++i) w[i] = *(const float2*)(W_edge + i * OUT_F + lane * 2);

    const int beg = row_start[n];
    const int end = beg + counts[n];

    float Swd[6] = {0.f, 0.f, 0.f, 0.f, 0.f, 0.f};
    float g0 = 0.f, g1 = 0.f;

    for (int p0 = beg; p0 < end; p0 += 64) {
        // ---- phase A: lane t handles edge p0+t ----
        const int t = p0 + lane;
        uint2 pe = (t < end) ? pedge[t] : make_uint2(0u, 0u);
        const unsigned dp = pe.y;
        const float nr = (dp != 0u) ? norm[pe.x] : 0.f;

        unsigned zm = 0;
#pragma unroll
        for (int i = 0; i < 6; ++i) {
            int d = (dp >> (4 * i)) & 15;
            if (d == 0) zm |= (1u << i);
            Swd[i] += nr * (float)d;
        }
        const int z = __popc(zm);
        const int ne = (dp == 0u) ? 0 : ((z <= 2) ? (1 + z) : (6 - z));

        int x = ne;
#pragma unroll
        for (int st = 1; st < 64; st <<= 1) {
            int v = __shfl_up(x, st);
            if (lane >= st) x += v;
        }
        const int excl = x - ne;
        const int total = __shfl(x, 63);

        if (ne) {
            const unsigned base = pe.x * (unsigned)PROWB;   // byte offset of P row
            int wp = excl;
            if (z <= 2) {
                el[wp++] = base + 768u;                     // + sum-slice (fp8)
#pragma unroll
                for (int i = 0; i < 6; ++i)
                    if ((zm >> i) & 1u) el[wp++] = (base + i * 128u) | 0x80000000u;  // - zero slices
            } else {
#pragma unroll
                for (int i = 0; i < 6; ++i)
                    if (!((zm >> i) & 1u)) el[wp++] = base + i * 128u;               // + nonzero slices
            }
        }
        asm volatile("s_waitcnt lgkmcnt(0)" ::: "memory");

        // ---- phase B: wave-uniform entries -> SGPR base, ushort gather + fp8 decode ----
        int j = 0;
        for (; j + 8 <= total; j += 8) {
            unsigned ev[8];
            unsigned short qv[8];
#pragma unroll
            for (int q = 0; q < 8; ++q)
                ev[q] = __builtin_amdgcn_readfirstlane(el[j + q]);
#pragma unroll
            for (int q = 0; q < 8; ++q)
                qv[q] = *(const unsigned short*)(PG + (ev[q] & 0x7fffffffu) + l2);
#pragma unroll
            for (int q = 0; q < 8; ++q) {
                f32x2 fq = __builtin_amdgcn_cvt_pk_f32_fp8((int)qv[q], false);
                float sg = __uint_as_float(0x3f800000u | (ev[q] & 0x80000000u));
                g0 = fmaf(sg, fq.x, g0);
                g1 = fmaf(sg, fq.y, g1);
            }
        }
        for (; j < total; ++j) {
            unsigned e0 = __builtin_amdgcn_readfirstlane(el[j]);
            unsigned short q0 = *(const unsigned short*)(PG + (e0 & 0x7fffffffu) + l2);
            f32x2 f0 = __builtin_amdgcn_cvt_pk_f32_fp8((int)q0, false);
            float sg = __uint_as_float(0x3f800000u | (e0 & 0x80000000u));
            g0 = fmaf(sg, f0.x, g0);
            g1 = fmaf(sg, f0.y, g1);
        }
    }

    // ---- reduce Swd across the wave, fold base term ----
    float b0 = 0.f, b1 = 0.f;
#pragma unroll
    for (int i = 0; i < 6; ++i) {
        float v = Swd[i];
#pragma unroll
        for (int st = 1; st < 64; st <<= 1) v += __shfl_xor(v, st);
        b0 = fmaf(v, w[i].x, b0);
        b1 = fmaf(v, w[i].y, b1);
    }

    // ---- fused epilogue: relu(accum*norm + self + bias), self is bf16 ----
    const unsigned us = *(const unsigned*)(PG + (size_t)n * PROWB + 896 + lane * 4);
    const float nd = norm[n];
    const float2 bv = *(const float2*)(bias + lane * 2);
    float2 o;
    o.x = fmaxf((g0 + b0) * nd + bf_lo(us) + bv.x, 0.f);
    o.y = fmaxf((g1 + b1) * nd + bf_hi(us) + bv.y, 0.f);
    *(float2*)(out + (size_t)n * OUT_F + lane * 2) = o;
}

extern "C" void kernel_launch(void* const* d_in, const int* in_sizes, int n_in,
                              void* d_out, int out_size, void* d_ws, size_t ws_size,
                              hipStream_t stream)
{
    const float* h       = (const float*)d_in[0];
    const float* degrees = (const float*)d_in[1];
    const float* norm    = (const float*)d_in[2];
    const int*   src     = (const int*)d_in[3];
    const int*   dst     = (const int*)d_in[4];
    const float* W_self  = (const float*)d_in[5];
    const float* b_self  = (const float*)d_in[6];
    const float* W_node  = (const float*)d_in[7];
    const float* b_node  = (const float*)d_in[8];
    const float* W_edge  = (const float*)d_in[9];
    const float* bias    = (const float*)d_in[10];
    float* out = (float*)d_out;

    const int N = in_sizes[2];   // norm [N,1]
    const int E = in_sizes[3];   // src [E]
    const int NB = (N + 255) / 256;

    char* ws = (char*)d_ws;
    size_t off = 0;
    auto alloc = [&](size_t sz) { size_t o = off; off = (off + sz + 255) & ~(size_t)255; return o; };
    char*           PG     = (char*)(ws + alloc((size_t)N * PROWB));               // 57.6 MB
    unsigned short* hb     = (unsigned short*)(ws + alloc((size_t)N * IN_F * 2));  // 25.6 MB
    unsigned short* Wt     = (unsigned short*)(ws + alloc((size_t)NCOLS * IN_F * 2));
    float*          bvec   = (float*)(ws + alloc(NCOLS * 4));
    int*            counts = (int*)(ws + alloc((size_t)N * 4));
    int*            offs   = (int*)(ws + alloc((size_t)N * 4));
    int*            cursor = (int*)(ws + alloc((size_t)N * 4));
    int*            bsum   = (int*)(ws + alloc((size_t)NB * 4));
    uint2*          pedge  = (uint2*)(ws + alloc((size_t)E * 8));                  // 6.4 MB

    hipMemsetAsync(counts, 0, (size_t)N * 4, stream);

    int t8 = N * (IN_F / 8);
    k_conv_h<<<(t8 + 255) / 256, 256, 0, stream>>>(h, hb, t8);

    int tw = IN_F * NCOLS;
    k_conv_w<<<(tw + 255) / 256, 256, 0, stream>>>(W_node, W_self, b_node, b_self, Wt, bvec, tw);

    const int R  = (N + BM - 1) / BM;
    const int RP = (R + 7) / 8;
    k_gemm<<<RP * 8 * 8, 256, 0, stream>>>(hb, Wt, bvec, norm, PG, N, RP);

    k_hist<<<(E + 255) / 256, 256, 0, stream>>>(dst, counts, E);
    k_scan_a<<<NB, 256, 0, stream>>>(counts, offs, bsum, N);
    k_scan_b<<<1, 256, 0, stream>>>(bsum, NB);
    k_scan_c<<<NB, 256, 0, stream>>>(offs, bsum, cursor, N);
    k_scatter<<<(E + 255) / 256, 256, 0, stream>>>(src, dst, degrees, cursor, pedge, E);

    k_aggregate<<<(N + 3) / 4, 256, 0, stream>>>(PG, offs, counts, pedge,
                                                 norm, W_edge, bias, out, N);
}